// Round 11
// baseline (108.456 us; speedup 1.0000x reference)
//
#include <hip/hip_runtime.h>
#include <math.h>

// Chamfer distance, B=4, H=W=128, HW=16384, threshold 0.1.
//
// r9/r10 post-mortem: raising rows/lane (RG 256/512) to relieve the LDS
// pipe always lost more in window economics (wider rho-span, fatter md_max,
// duplicated/split phase A) than it saved -- r8's RG=128 single-block shape
// is window-optimal. r11 keeps r8 VERBATIM except the column broadcast:
// staged columns are consumed at wave-uniform addresses (pure broadcast),
// so replace the LDS round-trip (3 ds_read_b128 / 4 cols on the CU's single
// shared LDS pipe -- the 2x bottleneck at 32 waves/CU) with
// __builtin_amdgcn_readlane from the already-loaded per-lane qc registers
// (VALU pipe, zero LDS; NOT __shfl which emits ds_bpermute = LDS pipe).
// Bit-exact: same fma association (inner qx*npx+qz, outer qy*npy+t), same
// (j,j+1) min-tree pairing, same batch->col mapping; readlane ignores exec
// and all lanes hold valid clamped/sentinel data -> absmax 0.0.
//
// ws layout (~4.7 MB):
//   [0,128)    int segcounts[8][4]
//   [256,+2MB) float4 pts[8][HW]     segmented semi-dense (seg s at s*4096)
//   [+512KB)   uint minarr[8][HW]    d^2 bits, slot-indexed
//   [+2MB)     float4 sorted[8][HW]  (x, y, z, slot_bits) rho-bucket order
//   [+8.2KB)   int binstart[8][257]
//   [+32KB)    int hist[8][4][256]

#define B_ 4
#define HW_ 16384
#define THRESH 0.1f
#define BIGF 1e30f
#define EPS_ 1e-12f

#define SEGCAP 4096
#define NSEG 4
#define NBIN 256
#define BINSCALE 0.25f   // bin = min(255, rho*0.25); width 4, covers rho<1024
#define BINW 4.0f
#define RG 128           // rows per pdist block (2/lane -- window-optimal, r8)
#define NW 8             // waves per pdist block (512 threads)
#define AWIN 1024        // phase-A window (cols)
#define PD_NGRP 128      // 128 groups x 128 rows covers n_from <= 16384

__device__ __forceinline__ float rdlane(float v, int j) {
    return __int_as_float(__builtin_amdgcn_readlane(__float_as_int(v), j));
}

// ---------------- compact + bin histogram (r6, proven) ----------------
__global__ __launch_bounds__(1024)
void compact_kernel(const float* __restrict__ in1, const float* __restrict__ in2,
                    int* __restrict__ segcounts, float4* __restrict__ pts,
                    uint4* __restrict__ minarr4, int* __restrict__ histG) {
    int seg = blockIdx.x, combo = blockIdx.y;
    int b = combo >> 1, s = combo & 1;
    int tid = threadIdx.x, lane = tid & 63, wid = tid >> 6;
    const float* in = s ? in2 : in1;
    int ibase = seg * SEGCAP + tid * 4;
    float4 v = ((const float4*)(in + b * HW_))[(unsigned)ibase >> 2];
    float w0 = v.x - THRESH, w1 = v.y - THRESH, w2 = v.z - THRESH, w3 = v.w - THRESH;
    int a0 = w0 > 0.f, a1 = w1 > 0.f, a2 = w2 > 0.f, a3 = w3 > 0.f;

    unsigned int bb = __float_as_uint(BIGF);
    minarr4[(unsigned)(combo * HW_ + ibase) >> 2] = make_uint4(bb, bb, bb, bb);

    __shared__ int hist[NBIN];
    if (tid < NBIN) hist[tid] = 0;

    int c = a0 + a1 + a2 + a3;
    int incl = c;
#pragma unroll
    for (int o = 1; o < 64; o <<= 1) {
        int x = __shfl_up(incl, o, 64);
        if (lane >= o) incl += x;
    }
    int wexcl = incl - c;
    __shared__ int wtot[16], wpre[17];
    if (lane == 63) wtot[wid] = incl;
    __syncthreads();                             // covers hist init too
    if (tid == 0) {
        int run = 0;
#pragma unroll
        for (int ww = 0; ww < 16; ++ww) { wpre[ww] = run; run += wtot[ww]; }
        wpre[16] = run;
    }
    __syncthreads();
    int off = wpre[wid] + wexcl;
    float4* dst = pts + combo * HW_ + seg * SEGCAP;
    float wv[4] = {w0, w1, w2, w3};
    int   av[4] = {a0, a1, a2, a3};
#pragma unroll
    for (int u = 0; u < 4; ++u) {
        if (av[u]) {
            int i = ibase + u;
            float qx = (float)(i >> 7) * wv[u];
            float qy = (float)(i & 127) * wv[u];
            float zz = qx * qx + qy * qy;
            dst[off] = make_float4(qx, qy, zz, 0.0f);
            int bin = min(NBIN - 1, (int)(sqrtf(zz) * BINSCALE));
            atomicAdd(&hist[bin], 1);
            ++off;
        }
    }
    if (tid == 0) segcounts[combo * 4 + seg] = wpre[16];
    __syncthreads();
    if (tid < NBIN)
        histG[(combo * NSEG + seg) * NBIN + tid] = hist[tid];
}

// ---------------- scatter: 1 block per (seg, combo) = 32 blocks (r6) -------
__global__ __launch_bounds__(512)
void scatter_kernel(const int* __restrict__ segcounts, const float4* __restrict__ pts,
                    const int* __restrict__ histG, float4* __restrict__ sorted,
                    int* __restrict__ binstartG) {
    int seg = blockIdx.x, combo = blockIdx.y;
    int tid = threadIdx.x;
    __shared__ int h[NSEG][NBIN];
    __shared__ int sc[NBIN];
    __shared__ int cur[NBIN];
    for (int i = tid; i < NSEG * NBIN; i += 512)
        h[i >> 8][i & 255] = histG[combo * NSEG * NBIN + i];
    __syncthreads();
    if (tid < NBIN) sc[tid] = h[0][tid] + h[1][tid] + h[2][tid] + h[3][tid];
    __syncthreads();
#pragma unroll
    for (int o = 1; o < NBIN; o <<= 1) {         // Hillis-Steele inclusive scan
        int v = (tid < NBIN && tid >= o) ? sc[tid - o] : 0;
        __syncthreads();
        if (tid < NBIN) sc[tid] += v;
        __syncthreads();
    }
    if (tid < NBIN) {
        int tot = h[0][tid] + h[1][tid] + h[2][tid] + h[3][tid];
        int excl = sc[tid] - tot;                // exclusive bin start
        int o2 = excl;
        for (int s2 = 0; s2 < seg; ++s2) o2 += h[s2][tid];   // seg-uniform
        cur[tid] = o2;
        if (seg == 0) binstartG[combo * (NBIN + 1) + tid] = excl;
    }
    if (seg == 0 && tid == 0)
        binstartG[combo * (NBIN + 1) + NBIN] = sc[NBIN - 1];  // n_active
    __syncthreads();
    int c = segcounts[combo * 4 + seg];
    const float4* src = pts + combo * HW_ + seg * SEGCAP;
    for (int i = tid; i < c; i += 512) {
        float4 p = src[i];
        int bin = min(NBIN - 1, (int)(sqrtf(p.z) * BINSCALE));
        int idx = atomicAdd(&cur[bin], 1);
        sorted[(size_t)combo * HW_ + idx] =
            make_float4(p.x, p.y, p.z, __uint_as_float((unsigned)(seg * SEGCAP + i)));
    }
}

// ---------------- pruned dist: 8 waves, 128 rows, readlane broadcast -------
__global__ __launch_bounds__(512, 4)
void pdist_kernel(const float4* __restrict__ sorted, const int* __restrict__ binstart,
                  unsigned int* __restrict__ minarr) {
    int grp = blockIdx.x, combo = blockIdx.y;
    int tid = threadIdx.x, lane = tid & 63, w = tid >> 6;
    int tc = combo ^ 1;
    int n_from = binstart[combo * (NBIN + 1) + NBIN];
    int n_to   = binstart[tc * (NBIN + 1) + NBIN];
    if (n_from <= 0 || n_to <= 0) return;        // reduce_out emits sentinel
    int rbase = grp * RG;
    if (rbase >= n_from) return;                 // block-uniform

    const float4* __restrict__ rows = sorted + (size_t)combo * HW_;
    const float4* __restrict__ cols = sorted + (size_t)tc * HW_;

    int r0 = rbase + lane, r1 = rbase + 64 + lane;
    bool v0 = r0 < n_from, v1 = r1 < n_from;
    float4 P0 = rows[min(r0, n_from - 1)];
    float4 P1 = rows[min(r1, n_from - 1)];
    float npx0 = -2.0f * P0.x, npy0 = -2.0f * P0.y, p20 = P0.z;
    float npx1 = -2.0f * P1.x, npy1 = -2.0f * P1.y, p21 = P1.z;
    unsigned int slot0 = __float_as_uint(P0.w);
    unsigned int slot1 = __float_as_uint(P1.w);
    float m0 = BIGF, m1 = BIGF;

    // group rho bounds from BIN BOUNDARIES (order-independent -- r6 fix)
    int blo_r = min(NBIN - 1, (int)(sqrtf(rows[rbase].z) * BINSCALE));
    int bhi_r = min(NBIN - 1, (int)(sqrtf(rows[min(rbase + RG - 1, n_from - 1)].z) * BINSCALE));
    float rho_lo = (float)blo_r * BINW;          // every row rho >= rho_lo
    float rho_hi = (float)(bhi_r + 1) * BINW;    // every row rho <  rho_hi

    // phase-A window centered on the rows' bin-range midpoint (r8)
    int jmid = (binstart[tc * (NBIN + 1) + blo_r]
                + binstart[tc * (NBIN + 1) + min(bhi_r + 1, NBIN)]) >> 1;
    int aHi = min(n_to, jmid + AWIN / 2);
    int aLo = max(0, aHi - AWIN);
    aHi = min(n_to, aLo + AWIN);

    __shared__ float mW[NW][RG];

    auto ld = [&](int jb) -> float4 {            // clamped batch element load
        int j = jb + lane;
        return (j < n_to) ? cols[j] : make_float4(0.0f, 0.0f, BIGF, 0.0f);
    };
    // Column broadcast from registers via readlane (VALU pipe, ZERO LDS --
    // the r8 LDS staging was the CU-level bottleneck). Same fma association
    // (inner qx*npx+qz, outer qy*npy+t) and same (j,j+1) min pairing as the
    // dense kernel -> identical bits.
    auto proc = [&](float4 qc) {
#pragma unroll
        for (int jj = 0; jj < 64; jj += 2) {
            float ax = rdlane(qc.x, jj),     ay = rdlane(qc.y, jj);
            float az = rdlane(qc.z, jj);
            float bx = rdlane(qc.x, jj + 1), by = rdlane(qc.y, jj + 1);
            float bz = rdlane(qc.z, jj + 1);
            float t0 = fmaf(ay, npy0, fmaf(ax, npx0, az));
            float u1 = fmaf(by, npy0, fmaf(bx, npx0, bz));
            m0 = fminf(m0, fminf(t0, u1));   // -> v_min3_f32
            float s0 = fmaf(ay, npy1, fmaf(ax, npx1, az));
            float s1 = fmaf(by, npy1, fmaf(bx, npx1, bz));
            m1 = fminf(m1, fminf(s0, s1));
        }
    };

    // ---- phase A: fixed window, wave-interleaved, prefetched (r8) ----
    int nbA = (aHi - aLo + 63) >> 6;
    float4 qn = (w < nbA) ? ld(aLo + (w << 6))
                          : make_float4(0.0f, 0.0f, BIGF, 0.0f);
    for (int bi = w; bi < nbA; bi += NW) {
        float4 qc = qn;
        if (bi + NW < nbA) qn = ld(aLo + ((bi + NW) << 6));  // hide under FMAs
        proc(qc);
    }

    mW[w][lane] = m0; mW[w][64 + lane] = m1;
    __syncthreads();
    float c0 = mW[0][lane], c1 = mW[0][64 + lane];
#pragma unroll
    for (int ww = 1; ww < NW; ++ww) {
        c0 = fminf(c0, mW[ww][lane]);
        c1 = fminf(c1, mW[ww][64 + lane]);
    }
    float md0 = v0 ? fmaxf(c0 + p20, 0.0f) : -1.0f;
    float md1 = v1 ? fmaxf(c1 + p21, 0.0f) : -1.0f;
    float g = fmaxf(md0, md1);                   // group md_max via wave reduce
#pragma unroll
    for (int o = 1; o < 64; o <<= 1) g = fmaxf(g, __shfl_xor(g, o));
    // identical in every wave/lane -> identical window on all threads

    // exclusion bound (r6 margin family, proven absmax==0): include every
    // col bin not provably excludable for any row; widen for float slop.
    float S = sqrtf((g + 1.0f) * (1.0f / 0.99f)) * 1.001f;
    int b_lo = max(0, (int)((rho_lo - S) * BINSCALE) - 1);
    int b_hi = min(NBIN, (int)((rho_hi + S) * BINSCALE) + 2);
    int jlo2 = binstart[tc * (NBIN + 1) + b_lo];
    int jhi2 = binstart[tc * (NBIN + 1) + b_hi];

    // ---- phase B: residual [jlo2,aLo) + [aHi,jhi2), check-free, prefetched
    m0 = c0; m1 = c1;
    int nbL = (max(0, aLo - jlo2) + 63) >> 6;
    int nbR = (max(0, jhi2 - aHi) + 63) >> 6;
    int nbB = nbL + nbR;
    auto jbB = [&](int bi) {
        return (bi < nbL) ? (jlo2 + (bi << 6)) : (aHi + ((bi - nbL) << 6));
    };
    qn = (w < nbB) ? ld(jbB(w)) : make_float4(0.0f, 0.0f, BIGF, 0.0f);
    for (int bi = w; bi < nbB; bi += NW) {
        float4 qc = qn;
        if (bi + NW < nbB) qn = ld(jbB(bi + NW));
        proc(qc);                                // overlap cols: min-idempotent
    }
    __syncthreads();                             // phase-A mW reads all done
    mW[w][lane] = m0; mW[w][64 + lane] = m1;
    __syncthreads();
    if (w == 0) {
        float f0 = mW[0][lane], f1 = mW[0][64 + lane];
#pragma unroll
        for (int ww = 1; ww < NW; ++ww) {
            f0 = fminf(f0, mW[ww][lane]);
            f1 = fminf(f1, mW[ww][64 + lane]);
        }
        if (v0) minarr[combo * HW_ + slot0] = __float_as_uint(fmaxf(f0 + p20, 0.0f));
        if (v1) minarr[combo * HW_ + slot1] = __float_as_uint(fmaxf(f1 + p21, 0.0f));
    }
}

// ---------------- reduce (unchanged: defines the absmax==0 sum order) -------
__global__ void reduce_out_kernel(const int* __restrict__ segcounts,
                                  const unsigned int* __restrict__ minarr,
                                  float* __restrict__ out) {
    int b = blockIdx.x;
    int tid = threadIdx.x;
    int d = tid >> 9;
    int t = tid & 511;
    int combo = b * 2 + d;

    float acc = 0.0f;
    for (int s = 0; s < NSEG; ++s) {
        int c = segcounts[combo * 4 + s];
        const unsigned int* ma = minarr + combo * HW_ + s * SEGCAP;
        for (int r = t; r < c; r += 512)
            acc += sqrtf(fmaxf(__uint_as_float(ma[r]), EPS_));
    }
#pragma unroll
    for (int o = 32; o >= 1; o >>= 1) acc += __shfl_down(acc, o);

    __shared__ float wsum[16];
    if ((tid & 63) == 0) wsum[tid >> 6] = acc;
    __syncthreads();
    if (tid == 0) {
        float s0 = 0.0f, s1 = 0.0f;
#pragma unroll
        for (int w = 0; w < 8; ++w)  s0 += wsum[w];
#pragma unroll
        for (int w = 8; w < 16; ++w) s1 += wsum[w];
        int n0 = 0, n1 = 0;
#pragma unroll
        for (int s = 0; s < NSEG; ++s) {
            n0 += segcounts[(b * 2) * 4 + s];
            n1 += segcounts[(b * 2 + 1) * 4 + s];
        }
        out[b] = (n0 > 0 && n1 > 0)
                 ? s0 / (float)n0 + s1 / (float)n1
                 : 1.0e6f;
    }
}

extern "C" void kernel_launch(void* const* d_in, const int* in_sizes, int n_in,
                              void* d_out, int out_size, void* d_ws, size_t ws_size,
                              hipStream_t stream) {
    const float* in1 = (const float*)d_in[0];
    const float* in2 = (const float*)d_in[1];
    float* out = (float*)d_out;
    char* ws = (char*)d_ws;
    int* segcounts = (int*)ws;
    float4* pts = (float4*)(ws + 256);
    size_t minoff = 256 + (size_t)8 * HW_ * sizeof(float4);
    unsigned int* minarr = (unsigned int*)(ws + minoff);
    size_t sortoff = minoff + (size_t)8 * HW_ * sizeof(unsigned int);
    float4* sorted = (float4*)(ws + sortoff);
    size_t binoff = sortoff + (size_t)8 * HW_ * sizeof(float4);
    int* binstart = (int*)(ws + binoff);
    size_t histoff = binoff + (size_t)8 * (NBIN + 1) * sizeof(int);
    int* histG = (int*)(ws + histoff);

    hipLaunchKernelGGL(compact_kernel, dim3(NSEG, 8), dim3(1024), 0, stream,
                       in1, in2, segcounts, pts, (uint4*)minarr, histG);
    hipLaunchKernelGGL(scatter_kernel, dim3(NSEG, 8), dim3(512), 0, stream,
                       segcounts, pts, histG, sorted, binstart);
    hipLaunchKernelGGL(pdist_kernel, dim3(PD_NGRP, 8), dim3(512), 0, stream,
                       sorted, binstart, minarr);
    hipLaunchKernelGGL(reduce_out_kernel, dim3(B_), dim3(1024), 0, stream,
                       segcounts, minarr, out);
}

// Round 12
// 80.592 us; speedup vs baseline: 1.3457x; 1.3457x over previous
//
#include <hip/hip_runtime.h>
#include <math.h>

// Chamfer distance, B=4, H=W=128, HW=16384, threshold 0.1.
//
// r11 post-mortem: removing ALL inner-loop LDS (readlane broadcast) made
// pdist SLOWER (83.7->108.5) -> LDS was never the bottleneck: the inner
// reads are wave-uniform broadcasts (same-address ds_read = ~bank-cycle
// cost, not the 12cy per-lane-distinct figure). readlane lost on SGPR
// round-trips (1-SGPR/instr rule -> extra v_movs) + longer dep chains.
// r8's structure is both window-optimal (r9/r10 bracketed RG) and
// pipe-balanced (r11). r12 = r8 VERBATIM + the one clean lever left:
// BINW 4->2 (NBIN 512). The r6-proven bound machinery is parameterized by
// BINW/BINSCALE and never depends on absolute width; the window's ~3-bin
// structural slack (+ quantization) halves from ~12-16 rho-units (~600-800
// excess cols/group) to ~6-8. Max rho ~740 < 1024 -> no clamp edge cases;
// all kernels bin via the identical expression.
//
// ws layout (~4.7 MB):
//   [0,128)    int segcounts[8][4]
//   [256,+2MB) float4 pts[8][HW]     segmented semi-dense (seg s at s*4096)
//   [+512KB)   uint minarr[8][HW]    d^2 bits, slot-indexed
//   [+2MB)     float4 sorted[8][HW]  (x, y, z, slot_bits) rho-bucket order
//   [+16.4KB)  int binstart[8][513]
//   [+64KB)    int hist[8][4][512]

#define B_ 4
#define HW_ 16384
#define THRESH 0.1f
#define BIGF 1e30f
#define EPS_ 1e-12f

#define SEGCAP 4096
#define NSEG 4
#define NBIN 512
#define BINSCALE 0.5f    // bin = min(511, rho*0.5); width 2, covers rho<1024
#define BINW 2.0f
#define RG 128           // rows per pdist block (2/lane -- window-optimal, r8)
#define NW 8             // waves per pdist block (512 threads)
#define AWIN 1024        // phase-A window (cols)
#define PD_NGRP 128      // 128 groups x 128 rows covers n_from <= 16384

// ---------------- compact + bin histogram (r6, proven) ----------------
__global__ __launch_bounds__(1024)
void compact_kernel(const float* __restrict__ in1, const float* __restrict__ in2,
                    int* __restrict__ segcounts, float4* __restrict__ pts,
                    uint4* __restrict__ minarr4, int* __restrict__ histG) {
    int seg = blockIdx.x, combo = blockIdx.y;
    int b = combo >> 1, s = combo & 1;
    int tid = threadIdx.x, lane = tid & 63, wid = tid >> 6;
    const float* in = s ? in2 : in1;
    int ibase = seg * SEGCAP + tid * 4;
    float4 v = ((const float4*)(in + b * HW_))[(unsigned)ibase >> 2];
    float w0 = v.x - THRESH, w1 = v.y - THRESH, w2 = v.z - THRESH, w3 = v.w - THRESH;
    int a0 = w0 > 0.f, a1 = w1 > 0.f, a2 = w2 > 0.f, a3 = w3 > 0.f;

    unsigned int bb = __float_as_uint(BIGF);
    minarr4[(unsigned)(combo * HW_ + ibase) >> 2] = make_uint4(bb, bb, bb, bb);

    __shared__ int hist[NBIN];
    if (tid < NBIN) hist[tid] = 0;

    int c = a0 + a1 + a2 + a3;
    int incl = c;
#pragma unroll
    for (int o = 1; o < 64; o <<= 1) {
        int x = __shfl_up(incl, o, 64);
        if (lane >= o) incl += x;
    }
    int wexcl = incl - c;
    __shared__ int wtot[16], wpre[17];
    if (lane == 63) wtot[wid] = incl;
    __syncthreads();                             // covers hist init too
    if (tid == 0) {
        int run = 0;
#pragma unroll
        for (int ww = 0; ww < 16; ++ww) { wpre[ww] = run; run += wtot[ww]; }
        wpre[16] = run;
    }
    __syncthreads();
    int off = wpre[wid] + wexcl;
    float4* dst = pts + combo * HW_ + seg * SEGCAP;
    float wv[4] = {w0, w1, w2, w3};
    int   av[4] = {a0, a1, a2, a3};
#pragma unroll
    for (int u = 0; u < 4; ++u) {
        if (av[u]) {
            int i = ibase + u;
            float qx = (float)(i >> 7) * wv[u];
            float qy = (float)(i & 127) * wv[u];
            float zz = qx * qx + qy * qy;
            dst[off] = make_float4(qx, qy, zz, 0.0f);
            int bin = min(NBIN - 1, (int)(sqrtf(zz) * BINSCALE));
            atomicAdd(&hist[bin], 1);
            ++off;
        }
    }
    if (tid == 0) segcounts[combo * 4 + seg] = wpre[16];
    __syncthreads();
    if (tid < NBIN)
        histG[(combo * NSEG + seg) * NBIN + tid] = hist[tid];
}

// ---------------- scatter: 1 block per (seg, combo) = 32 blocks (r6) -------
__global__ __launch_bounds__(512)
void scatter_kernel(const int* __restrict__ segcounts, const float4* __restrict__ pts,
                    const int* __restrict__ histG, float4* __restrict__ sorted,
                    int* __restrict__ binstartG) {
    int seg = blockIdx.x, combo = blockIdx.y;
    int tid = threadIdx.x;
    __shared__ int h[NSEG][NBIN];
    __shared__ int sc[NBIN];
    __shared__ int cur[NBIN];
    for (int i = tid; i < NSEG * NBIN; i += 512)
        h[i >> 9][i & (NBIN - 1)] = histG[combo * NSEG * NBIN + i];
    __syncthreads();
    if (tid < NBIN) sc[tid] = h[0][tid] + h[1][tid] + h[2][tid] + h[3][tid];
    __syncthreads();
#pragma unroll
    for (int o = 1; o < NBIN; o <<= 1) {         // Hillis-Steele inclusive scan
        int v = (tid < NBIN && tid >= o) ? sc[tid - o] : 0;
        __syncthreads();
        if (tid < NBIN) sc[tid] += v;
        __syncthreads();
    }
    if (tid < NBIN) {
        int tot = h[0][tid] + h[1][tid] + h[2][tid] + h[3][tid];
        int excl = sc[tid] - tot;                // exclusive bin start
        int o2 = excl;
        for (int s2 = 0; s2 < seg; ++s2) o2 += h[s2][tid];   // seg-uniform
        cur[tid] = o2;
        if (seg == 0) binstartG[combo * (NBIN + 1) + tid] = excl;
    }
    if (seg == 0 && tid == 0)
        binstartG[combo * (NBIN + 1) + NBIN] = sc[NBIN - 1];  // n_active
    __syncthreads();
    int c = segcounts[combo * 4 + seg];
    const float4* src = pts + combo * HW_ + seg * SEGCAP;
    for (int i = tid; i < c; i += 512) {
        float4 p = src[i];
        int bin = min(NBIN - 1, (int)(sqrtf(p.z) * BINSCALE));
        int idx = atomicAdd(&cur[bin], 1);
        sorted[(size_t)combo * HW_ + idx] =
            make_float4(p.x, p.y, p.z, __uint_as_float((unsigned)(seg * SEGCAP + i)));
    }
}

// ---------------- pruned dist: 8 waves/block, 128 rows, 2 phases (r8) ------
__global__ __launch_bounds__(512, 4)   // VGPR cap 128: prefetch fits, no spill
void pdist_kernel(const float4* __restrict__ sorted, const int* __restrict__ binstart,
                  unsigned int* __restrict__ minarr) {
    int grp = blockIdx.x, combo = blockIdx.y;
    int tid = threadIdx.x, lane = tid & 63, w = tid >> 6;
    int tc = combo ^ 1;
    int n_from = binstart[combo * (NBIN + 1) + NBIN];
    int n_to   = binstart[tc * (NBIN + 1) + NBIN];
    if (n_from <= 0 || n_to <= 0) return;        // reduce_out emits sentinel
    int rbase = grp * RG;
    if (rbase >= n_from) return;                 // block-uniform

    const float4* __restrict__ rows = sorted + (size_t)combo * HW_;
    const float4* __restrict__ cols = sorted + (size_t)tc * HW_;

    int r0 = rbase + lane, r1 = rbase + 64 + lane;
    bool v0 = r0 < n_from, v1 = r1 < n_from;
    float4 P0 = rows[min(r0, n_from - 1)];
    float4 P1 = rows[min(r1, n_from - 1)];
    float npx0 = -2.0f * P0.x, npy0 = -2.0f * P0.y, p20 = P0.z;
    float npx1 = -2.0f * P1.x, npy1 = -2.0f * P1.y, p21 = P1.z;
    unsigned int slot0 = __float_as_uint(P0.w);
    unsigned int slot1 = __float_as_uint(P1.w);
    float m0 = BIGF, m1 = BIGF;

    // group rho bounds from BIN BOUNDARIES (order-independent -- r6 fix)
    int blo_r = min(NBIN - 1, (int)(sqrtf(rows[rbase].z) * BINSCALE));
    int bhi_r = min(NBIN - 1, (int)(sqrtf(rows[min(rbase + RG - 1, n_from - 1)].z) * BINSCALE));
    float rho_lo = (float)blo_r * BINW;          // every row rho >= rho_lo
    float rho_hi = (float)(bhi_r + 1) * BINW;    // every row rho <  rho_hi

    // phase-A window centered on the rows' bin-range midpoint (r8)
    int jmid = (binstart[tc * (NBIN + 1) + blo_r]
                + binstart[tc * (NBIN + 1) + min(bhi_r + 1, NBIN)]) >> 1;
    int aHi = min(n_to, jmid + AWIN / 2);
    int aLo = max(0, aHi - AWIN);
    aHi = min(n_to, aLo + AWIN);

    __shared__ __align__(16) float bx[NW][64], by[NW][64], bz[NW][64];
    __shared__ float mW[NW][RG];

    auto ld = [&](int jb) -> float4 {            // clamped batch element load
        int j = jb + lane;
        return (j < n_to) ? cols[j] : make_float4(0.0f, 0.0f, BIGF, 0.0f);
    };
    // stage a preloaded batch into this wave's LDS stripe and min-reduce.
    // Reads are wave-uniform broadcasts (cheap -- r11 proved the LDS pipe
    // is not the bottleneck). Inner math VERBATIM dense -> same bits.
    auto proc = [&](float4 qc) {
        bx[w][lane] = qc.x; by[w][lane] = qc.y; bz[w][lane] = qc.z;
        const float4* X = (const float4*)bx[w];
        const float4* Y = (const float4*)by[w];
        const float4* Z = (const float4*)bz[w];
#pragma unroll
        for (int q4 = 0; q4 < 16; ++q4) {
            float4 qx = X[q4], qy = Y[q4], qz = Z[q4];
            float t0 = fmaf(qy.x, npy0, fmaf(qx.x, npx0, qz.x));
            float u1 = fmaf(qy.y, npy0, fmaf(qx.y, npx0, qz.y));
            m0 = fminf(m0, fminf(t0, u1));
            float u2 = fmaf(qy.z, npy0, fmaf(qx.z, npx0, qz.z));
            float u3 = fmaf(qy.w, npy0, fmaf(qx.w, npx0, qz.w));
            m0 = fminf(m0, fminf(u2, u3));
            float s0 = fmaf(qy.x, npy1, fmaf(qx.x, npx1, qz.x));
            float s1 = fmaf(qy.y, npy1, fmaf(qx.y, npx1, qz.y));
            m1 = fminf(m1, fminf(s0, s1));
            float s2 = fmaf(qy.z, npy1, fmaf(qx.z, npx1, qz.z));
            float s3 = fmaf(qy.w, npy1, fmaf(qx.w, npx1, qz.w));
            m1 = fminf(m1, fminf(s2, s3));
        }
    };

    // ---- phase A: fixed window, wave-interleaved, prefetched ----
    int nbA = (aHi - aLo + 63) >> 6;
    float4 qn = (w < nbA) ? ld(aLo + (w << 6))
                          : make_float4(0.0f, 0.0f, BIGF, 0.0f);
    for (int bi = w; bi < nbA; bi += NW) {
        float4 qc = qn;
        if (bi + NW < nbA) qn = ld(aLo + ((bi + NW) << 6));  // hide under FMAs
        proc(qc);
    }

    mW[w][lane] = m0; mW[w][64 + lane] = m1;
    __syncthreads();
    float c0 = mW[0][lane], c1 = mW[0][64 + lane];
#pragma unroll
    for (int ww = 1; ww < NW; ++ww) {
        c0 = fminf(c0, mW[ww][lane]);
        c1 = fminf(c1, mW[ww][64 + lane]);
    }
    float md0 = v0 ? fmaxf(c0 + p20, 0.0f) : -1.0f;
    float md1 = v1 ? fmaxf(c1 + p21, 0.0f) : -1.0f;
    float g = fmaxf(md0, md1);                   // group md_max via wave reduce
#pragma unroll
    for (int o = 1; o < 64; o <<= 1) g = fmaxf(g, __shfl_xor(g, o));
    // identical in every wave/lane -> identical window on all threads

    // exclusion bound (r6 margin family, proven absmax==0): include every
    // col bin not provably excludable for any row; widen for float slop.
    float S = sqrtf((g + 1.0f) * (1.0f / 0.99f)) * 1.001f;
    int b_lo = max(0, (int)((rho_lo - S) * BINSCALE) - 1);
    int b_hi = min(NBIN, (int)((rho_hi + S) * BINSCALE) + 2);
    int jlo2 = binstart[tc * (NBIN + 1) + b_lo];
    int jhi2 = binstart[tc * (NBIN + 1) + b_hi];

    // ---- phase B: residual [jlo2,aLo) + [aHi,jhi2), check-free, prefetched
    m0 = c0; m1 = c1;
    int nbL = (max(0, aLo - jlo2) + 63) >> 6;
    int nbR = (max(0, jhi2 - aHi) + 63) >> 6;
    int nbB = nbL + nbR;
    auto jbB = [&](int bi) {
        return (bi < nbL) ? (jlo2 + (bi << 6)) : (aHi + ((bi - nbL) << 6));
    };
    qn = (w < nbB) ? ld(jbB(w)) : make_float4(0.0f, 0.0f, BIGF, 0.0f);
    for (int bi = w; bi < nbB; bi += NW) {
        float4 qc = qn;
        if (bi + NW < nbB) qn = ld(jbB(bi + NW));
        proc(qc);                                // overlap cols: min-idempotent
    }
    __syncthreads();                             // phase-A mW reads all done
    mW[w][lane] = m0; mW[w][64 + lane] = m1;
    __syncthreads();
    if (w == 0) {
        float f0 = mW[0][lane], f1 = mW[0][64 + lane];
#pragma unroll
        for (int ww = 1; ww < NW; ++ww) {
            f0 = fminf(f0, mW[ww][lane]);
            f1 = fminf(f1, mW[ww][64 + lane]);
        }
        if (v0) minarr[combo * HW_ + slot0] = __float_as_uint(fmaxf(f0 + p20, 0.0f));
        if (v1) minarr[combo * HW_ + slot1] = __float_as_uint(fmaxf(f1 + p21, 0.0f));
    }
}

// ---------------- reduce (unchanged: defines the absmax==0 sum order) -------
__global__ void reduce_out_kernel(const int* __restrict__ segcounts,
                                  const unsigned int* __restrict__ minarr,
                                  float* __restrict__ out) {
    int b = blockIdx.x;
    int tid = threadIdx.x;
    int d = tid >> 9;
    int t = tid & 511;
    int combo = b * 2 + d;

    float acc = 0.0f;
    for (int s = 0; s < NSEG; ++s) {
        int c = segcounts[combo * 4 + s];
        const unsigned int* ma = minarr + combo * HW_ + s * SEGCAP;
        for (int r = t; r < c; r += 512)
            acc += sqrtf(fmaxf(__uint_as_float(ma[r]), EPS_));
    }
#pragma unroll
    for (int o = 32; o >= 1; o >>= 1) acc += __shfl_down(acc, o);

    __shared__ float wsum[16];
    if ((tid & 63) == 0) wsum[tid >> 6] = acc;
    __syncthreads();
    if (tid == 0) {
        float s0 = 0.0f, s1 = 0.0f;
#pragma unroll
        for (int w = 0; w < 8; ++w)  s0 += wsum[w];
#pragma unroll
        for (int w = 8; w < 16; ++w) s1 += wsum[w];
        int n0 = 0, n1 = 0;
#pragma unroll
        for (int s = 0; s < NSEG; ++s) {
            n0 += segcounts[(b * 2) * 4 + s];
            n1 += segcounts[(b * 2 + 1) * 4 + s];
        }
        out[b] = (n0 > 0 && n1 > 0)
                 ? s0 / (float)n0 + s1 / (float)n1
                 : 1.0e6f;
    }
}

extern "C" void kernel_launch(void* const* d_in, const int* in_sizes, int n_in,
                              void* d_out, int out_size, void* d_ws, size_t ws_size,
                              hipStream_t stream) {
    const float* in1 = (const float*)d_in[0];
    const float* in2 = (const float*)d_in[1];
    float* out = (float*)d_out;
    char* ws = (char*)d_ws;
    int* segcounts = (int*)ws;
    float4* pts = (float4*)(ws + 256);
    size_t minoff = 256 + (size_t)8 * HW_ * sizeof(float4);
    unsigned int* minarr = (unsigned int*)(ws + minoff);
    size_t sortoff = minoff + (size_t)8 * HW_ * sizeof(unsigned int);
    float4* sorted = (float4*)(ws + sortoff);
    size_t binoff = sortoff + (size_t)8 * HW_ * sizeof(float4);
    int* binstart = (int*)(ws + binoff);
    size_t histoff = binoff + (size_t)8 * (NBIN + 1) * sizeof(int);
    int* histG = (int*)(ws + histoff);

    hipLaunchKernelGGL(compact_kernel, dim3(NSEG, 8), dim3(1024), 0, stream,
                       in1, in2, segcounts, pts, (uint4*)minarr, histG);
    hipLaunchKernelGGL(scatter_kernel, dim3(NSEG, 8), dim3(512), 0, stream,
                       segcounts, pts, histG, sorted, binstart);
    hipLaunchKernelGGL(pdist_kernel, dim3(PD_NGRP, 8), dim3(512), 0, stream,
                       sorted, binstart, minarr);
    hipLaunchKernelGGL(reduce_out_kernel, dim3(B_), dim3(1024), 0, stream,
                       segcounts, minarr, out);
}

// Round 13
// 79.069 us; speedup vs baseline: 1.3717x; 1.0193x over previous
//
#include <hip/hip_runtime.h>
#include <math.h>

// Chamfer distance, B=4, H=W=128, HW=16384, threshold 0.1.
//
// r12 post-mortem: BINW 4->2 WIN (83.7->80.6, absmax 0.0) -- window slack
// is the remaining controllable fat, and the r6 bound machinery is
// bin-width-independent (now twice-verified). At BINW=2 the needed window
// (~850 cols) dropped BELOW the fixed AWIN=1024 -> phase A itself now
// overshoots. r13: BINW 2->1 (NBIN 1024; halves the 3-bin structural slack
// again; max rho ~810 < 1024 so no clamp) + AWIN 1024->768 (total visits
// ~ max(AWIN, window); smaller A with a centered window keeps md quality,
// and any md inflation only widens B -- correctness unaffected). Scatter
// runs 1024 threads with NBIN-parameterized indexing. pdist inner loop,
// phases, bound formula, reduce: VERBATIM r12 (absmax-0.0 pedigree).
//
// ws layout (~4.9 MB):
//   [0,128)    int segcounts[8][4]
//   [256,+2MB) float4 pts[8][HW]     segmented semi-dense (seg s at s*4096)
//   [+512KB)   uint minarr[8][HW]    d^2 bits, slot-indexed
//   [+2MB)     float4 sorted[8][HW]  (x, y, z, slot_bits) rho-bucket order
//   [+32.8KB)  int binstart[8][1025]
//   [+128KB)   int hist[8][4][1024]

#define B_ 4
#define HW_ 16384
#define THRESH 0.1f
#define BIGF 1e30f
#define EPS_ 1e-12f

#define SEGCAP 4096
#define NSEG 4
#define NBIN 1024
#define BINSCALE 1.0f    // bin = min(1023, rho); width 1, covers rho<1024
#define BINW 1.0f
#define RG 128           // rows per pdist block (2/lane -- window-optimal, r8)
#define NW 8             // waves per pdist block (512 threads)
#define AWIN 768         // phase-A window (cols); needed window ~700-750
#define PD_NGRP 128      // 128 groups x 128 rows covers n_from <= 16384

// ---------------- compact + bin histogram (r6, proven) ----------------
__global__ __launch_bounds__(1024)
void compact_kernel(const float* __restrict__ in1, const float* __restrict__ in2,
                    int* __restrict__ segcounts, float4* __restrict__ pts,
                    uint4* __restrict__ minarr4, int* __restrict__ histG) {
    int seg = blockIdx.x, combo = blockIdx.y;
    int b = combo >> 1, s = combo & 1;
    int tid = threadIdx.x, lane = tid & 63, wid = tid >> 6;
    const float* in = s ? in2 : in1;
    int ibase = seg * SEGCAP + tid * 4;
    float4 v = ((const float4*)(in + b * HW_))[(unsigned)ibase >> 2];
    float w0 = v.x - THRESH, w1 = v.y - THRESH, w2 = v.z - THRESH, w3 = v.w - THRESH;
    int a0 = w0 > 0.f, a1 = w1 > 0.f, a2 = w2 > 0.f, a3 = w3 > 0.f;

    unsigned int bb = __float_as_uint(BIGF);
    minarr4[(unsigned)(combo * HW_ + ibase) >> 2] = make_uint4(bb, bb, bb, bb);

    __shared__ int hist[NBIN];
    if (tid < NBIN) hist[tid] = 0;

    int c = a0 + a1 + a2 + a3;
    int incl = c;
#pragma unroll
    for (int o = 1; o < 64; o <<= 1) {
        int x = __shfl_up(incl, o, 64);
        if (lane >= o) incl += x;
    }
    int wexcl = incl - c;
    __shared__ int wtot[16], wpre[17];
    if (lane == 63) wtot[wid] = incl;
    __syncthreads();                             // covers hist init too
    if (tid == 0) {
        int run = 0;
#pragma unroll
        for (int ww = 0; ww < 16; ++ww) { wpre[ww] = run; run += wtot[ww]; }
        wpre[16] = run;
    }
    __syncthreads();
    int off = wpre[wid] + wexcl;
    float4* dst = pts + combo * HW_ + seg * SEGCAP;
    float wv[4] = {w0, w1, w2, w3};
    int   av[4] = {a0, a1, a2, a3};
#pragma unroll
    for (int u = 0; u < 4; ++u) {
        if (av[u]) {
            int i = ibase + u;
            float qx = (float)(i >> 7) * wv[u];
            float qy = (float)(i & 127) * wv[u];
            float zz = qx * qx + qy * qy;
            dst[off] = make_float4(qx, qy, zz, 0.0f);
            int bin = min(NBIN - 1, (int)(sqrtf(zz) * BINSCALE));
            atomicAdd(&hist[bin], 1);
            ++off;
        }
    }
    if (tid == 0) segcounts[combo * 4 + seg] = wpre[16];
    __syncthreads();
    if (tid < NBIN)
        histG[(combo * NSEG + seg) * NBIN + tid] = hist[tid];
}

// ---------------- scatter: 1 block per (seg, combo) = 32 blocks (r6) -------
__global__ __launch_bounds__(1024)
void scatter_kernel(const int* __restrict__ segcounts, const float4* __restrict__ pts,
                    const int* __restrict__ histG, float4* __restrict__ sorted,
                    int* __restrict__ binstartG) {
    int seg = blockIdx.x, combo = blockIdx.y;
    int tid = threadIdx.x;
    __shared__ int h[NSEG][NBIN];
    __shared__ int sc[NBIN];
    __shared__ int cur[NBIN];
    for (int i = tid; i < NSEG * NBIN; i += 1024)
        h[i >> 10][i & (NBIN - 1)] = histG[combo * NSEG * NBIN + i];
    __syncthreads();
    if (tid < NBIN) sc[tid] = h[0][tid] + h[1][tid] + h[2][tid] + h[3][tid];
    __syncthreads();
#pragma unroll
    for (int o = 1; o < NBIN; o <<= 1) {         // Hillis-Steele inclusive scan
        int v = (tid < NBIN && tid >= o) ? sc[tid - o] : 0;
        __syncthreads();
        if (tid < NBIN) sc[tid] += v;
        __syncthreads();
    }
    if (tid < NBIN) {
        int tot = h[0][tid] + h[1][tid] + h[2][tid] + h[3][tid];
        int excl = sc[tid] - tot;                // exclusive bin start
        int o2 = excl;
        for (int s2 = 0; s2 < seg; ++s2) o2 += h[s2][tid];   // seg-uniform
        cur[tid] = o2;
        if (seg == 0) binstartG[combo * (NBIN + 1) + tid] = excl;
    }
    if (seg == 0 && tid == 0)
        binstartG[combo * (NBIN + 1) + NBIN] = sc[NBIN - 1];  // n_active
    __syncthreads();
    int c = segcounts[combo * 4 + seg];
    const float4* src = pts + combo * HW_ + seg * SEGCAP;
    for (int i = tid; i < c; i += 1024) {
        float4 p = src[i];
        int bin = min(NBIN - 1, (int)(sqrtf(p.z) * BINSCALE));
        int idx = atomicAdd(&cur[bin], 1);
        sorted[(size_t)combo * HW_ + idx] =
            make_float4(p.x, p.y, p.z, __uint_as_float((unsigned)(seg * SEGCAP + i)));
    }
}

// ---------------- pruned dist: 8 waves/block, 128 rows, 2 phases (r8) ------
__global__ __launch_bounds__(512, 4)   // VGPR cap 128: prefetch fits, no spill
void pdist_kernel(const float4* __restrict__ sorted, const int* __restrict__ binstart,
                  unsigned int* __restrict__ minarr) {
    int grp = blockIdx.x, combo = blockIdx.y;
    int tid = threadIdx.x, lane = tid & 63, w = tid >> 6;
    int tc = combo ^ 1;
    int n_from = binstart[combo * (NBIN + 1) + NBIN];
    int n_to   = binstart[tc * (NBIN + 1) + NBIN];
    if (n_from <= 0 || n_to <= 0) return;        // reduce_out emits sentinel
    int rbase = grp * RG;
    if (rbase >= n_from) return;                 // block-uniform

    const float4* __restrict__ rows = sorted + (size_t)combo * HW_;
    const float4* __restrict__ cols = sorted + (size_t)tc * HW_;

    int r0 = rbase + lane, r1 = rbase + 64 + lane;
    bool v0 = r0 < n_from, v1 = r1 < n_from;
    float4 P0 = rows[min(r0, n_from - 1)];
    float4 P1 = rows[min(r1, n_from - 1)];
    float npx0 = -2.0f * P0.x, npy0 = -2.0f * P0.y, p20 = P0.z;
    float npx1 = -2.0f * P1.x, npy1 = -2.0f * P1.y, p21 = P1.z;
    unsigned int slot0 = __float_as_uint(P0.w);
    unsigned int slot1 = __float_as_uint(P1.w);
    float m0 = BIGF, m1 = BIGF;

    // group rho bounds from BIN BOUNDARIES (order-independent -- r6 fix)
    int blo_r = min(NBIN - 1, (int)(sqrtf(rows[rbase].z) * BINSCALE));
    int bhi_r = min(NBIN - 1, (int)(sqrtf(rows[min(rbase + RG - 1, n_from - 1)].z) * BINSCALE));
    float rho_lo = (float)blo_r * BINW;          // every row rho >= rho_lo
    float rho_hi = (float)(bhi_r + 1) * BINW;    // every row rho <  rho_hi

    // phase-A window centered on the rows' bin-range midpoint (r8)
    int jmid = (binstart[tc * (NBIN + 1) + blo_r]
                + binstart[tc * (NBIN + 1) + min(bhi_r + 1, NBIN)]) >> 1;
    int aHi = min(n_to, jmid + AWIN / 2);
    int aLo = max(0, aHi - AWIN);
    aHi = min(n_to, aLo + AWIN);

    __shared__ __align__(16) float bx[NW][64], by[NW][64], bz[NW][64];
    __shared__ float mW[NW][RG];

    auto ld = [&](int jb) -> float4 {            // clamped batch element load
        int j = jb + lane;
        return (j < n_to) ? cols[j] : make_float4(0.0f, 0.0f, BIGF, 0.0f);
    };
    // stage a preloaded batch into this wave's LDS stripe and min-reduce.
    // Reads are wave-uniform broadcasts (cheap -- r11 proved the LDS pipe
    // is not the bottleneck). Inner math VERBATIM dense -> same bits.
    auto proc = [&](float4 qc) {
        bx[w][lane] = qc.x; by[w][lane] = qc.y; bz[w][lane] = qc.z;
        const float4* X = (const float4*)bx[w];
        const float4* Y = (const float4*)by[w];
        const float4* Z = (const float4*)bz[w];
#pragma unroll
        for (int q4 = 0; q4 < 16; ++q4) {
            float4 qx = X[q4], qy = Y[q4], qz = Z[q4];
            float t0 = fmaf(qy.x, npy0, fmaf(qx.x, npx0, qz.x));
            float u1 = fmaf(qy.y, npy0, fmaf(qx.y, npx0, qz.y));
            m0 = fminf(m0, fminf(t0, u1));
            float u2 = fmaf(qy.z, npy0, fmaf(qx.z, npx0, qz.z));
            float u3 = fmaf(qy.w, npy0, fmaf(qx.w, npx0, qz.w));
            m0 = fminf(m0, fminf(u2, u3));
            float s0 = fmaf(qy.x, npy1, fmaf(qx.x, npx1, qz.x));
            float s1 = fmaf(qy.y, npy1, fmaf(qx.y, npx1, qz.y));
            m1 = fminf(m1, fminf(s0, s1));
            float s2 = fmaf(qy.z, npy1, fmaf(qx.z, npx1, qz.z));
            float s3 = fmaf(qy.w, npy1, fmaf(qx.w, npx1, qz.w));
            m1 = fminf(m1, fminf(s2, s3));
        }
    };

    // ---- phase A: fixed window, wave-interleaved, prefetched ----
    int nbA = (aHi - aLo + 63) >> 6;
    float4 qn = (w < nbA) ? ld(aLo + (w << 6))
                          : make_float4(0.0f, 0.0f, BIGF, 0.0f);
    for (int bi = w; bi < nbA; bi += NW) {
        float4 qc = qn;
        if (bi + NW < nbA) qn = ld(aLo + ((bi + NW) << 6));  // hide under FMAs
        proc(qc);
    }

    mW[w][lane] = m0; mW[w][64 + lane] = m1;
    __syncthreads();
    float c0 = mW[0][lane], c1 = mW[0][64 + lane];
#pragma unroll
    for (int ww = 1; ww < NW; ++ww) {
        c0 = fminf(c0, mW[ww][lane]);
        c1 = fminf(c1, mW[ww][64 + lane]);
    }
    float md0 = v0 ? fmaxf(c0 + p20, 0.0f) : -1.0f;
    float md1 = v1 ? fmaxf(c1 + p21, 0.0f) : -1.0f;
    float g = fmaxf(md0, md1);                   // group md_max via wave reduce
#pragma unroll
    for (int o = 1; o < 64; o <<= 1) g = fmaxf(g, __shfl_xor(g, o));
    // identical in every wave/lane -> identical window on all threads

    // exclusion bound (r6 margin family, proven absmax==0): include every
    // col bin not provably excludable for any row; widen for float slop.
    float S = sqrtf((g + 1.0f) * (1.0f / 0.99f)) * 1.001f;
    int b_lo = max(0, (int)((rho_lo - S) * BINSCALE) - 1);
    int b_hi = min(NBIN, (int)((rho_hi + S) * BINSCALE) + 2);
    int jlo2 = binstart[tc * (NBIN + 1) + b_lo];
    int jhi2 = binstart[tc * (NBIN + 1) + b_hi];

    // ---- phase B: residual [jlo2,aLo) + [aHi,jhi2), check-free, prefetched
    m0 = c0; m1 = c1;
    int nbL = (max(0, aLo - jlo2) + 63) >> 6;
    int nbR = (max(0, jhi2 - aHi) + 63) >> 6;
    int nbB = nbL + nbR;
    auto jbB = [&](int bi) {
        return (bi < nbL) ? (jlo2 + (bi << 6)) : (aHi + ((bi - nbL) << 6));
    };
    qn = (w < nbB) ? ld(jbB(w)) : make_float4(0.0f, 0.0f, BIGF, 0.0f);
    for (int bi = w; bi < nbB; bi += NW) {
        float4 qc = qn;
        if (bi + NW < nbB) qn = ld(jbB(bi + NW));
        proc(qc);                                // overlap cols: min-idempotent
    }
    __syncthreads();                             // phase-A mW reads all done
    mW[w][lane] = m0; mW[w][64 + lane] = m1;
    __syncthreads();
    if (w == 0) {
        float f0 = mW[0][lane], f1 = mW[0][64 + lane];
#pragma unroll
        for (int ww = 1; ww < NW; ++ww) {
            f0 = fminf(f0, mW[ww][lane]);
            f1 = fminf(f1, mW[ww][64 + lane]);
        }
        if (v0) minarr[combo * HW_ + slot0] = __float_as_uint(fmaxf(f0 + p20, 0.0f));
        if (v1) minarr[combo * HW_ + slot1] = __float_as_uint(fmaxf(f1 + p21, 0.0f));
    }
}

// ---------------- reduce (unchanged: defines the absmax==0 sum order) -------
__global__ void reduce_out_kernel(const int* __restrict__ segcounts,
                                  const unsigned int* __restrict__ minarr,
                                  float* __restrict__ out) {
    int b = blockIdx.x;
    int tid = threadIdx.x;
    int d = tid >> 9;
    int t = tid & 511;
    int combo = b * 2 + d;

    float acc = 0.0f;
    for (int s = 0; s < NSEG; ++s) {
        int c = segcounts[combo * 4 + s];
        const unsigned int* ma = minarr + combo * HW_ + s * SEGCAP;
        for (int r = t; r < c; r += 512)
            acc += sqrtf(fmaxf(__uint_as_float(ma[r]), EPS_));
    }
#pragma unroll
    for (int o = 32; o >= 1; o >>= 1) acc += __shfl_down(acc, o);

    __shared__ float wsum[16];
    if ((tid & 63) == 0) wsum[tid >> 6] = acc;
    __syncthreads();
    if (tid == 0) {
        float s0 = 0.0f, s1 = 0.0f;
#pragma unroll
        for (int w = 0; w < 8; ++w)  s0 += wsum[w];
#pragma unroll
        for (int w = 8; w < 16; ++w) s1 += wsum[w];
        int n0 = 0, n1 = 0;
#pragma unroll
        for (int s = 0; s < NSEG; ++s) {
            n0 += segcounts[(b * 2) * 4 + s];
            n1 += segcounts[(b * 2 + 1) * 4 + s];
        }
        out[b] = (n0 > 0 && n1 > 0)
                 ? s0 / (float)n0 + s1 / (float)n1
                 : 1.0e6f;
    }
}

extern "C" void kernel_launch(void* const* d_in, const int* in_sizes, int n_in,
                              void* d_out, int out_size, void* d_ws, size_t ws_size,
                              hipStream_t stream) {
    const float* in1 = (const float*)d_in[0];
    const float* in2 = (const float*)d_in[1];
    float* out = (float*)d_out;
    char* ws = (char*)d_ws;
    int* segcounts = (int*)ws;
    float4* pts = (float4*)(ws + 256);
    size_t minoff = 256 + (size_t)8 * HW_ * sizeof(float4);
    unsigned int* minarr = (unsigned int*)(ws + minoff);
    size_t sortoff = minoff + (size_t)8 * HW_ * sizeof(unsigned int);
    float4* sorted = (float4*)(ws + sortoff);
    size_t binoff = sortoff + (size_t)8 * HW_ * sizeof(float4);
    int* binstart = (int*)(ws + binoff);
    size_t histoff = binoff + (size_t)8 * (NBIN + 1) * sizeof(int);
    int* histG = (int*)(ws + histoff);

    hipLaunchKernelGGL(compact_kernel, dim3(NSEG, 8), dim3(1024), 0, stream,
                       in1, in2, segcounts, pts, (uint4*)minarr, histG);
    hipLaunchKernelGGL(scatter_kernel, dim3(NSEG, 8), dim3(1024), 0, stream,
                       segcounts, pts, histG, sorted, binstart);
    hipLaunchKernelGGL(pdist_kernel, dim3(PD_NGRP, 8), dim3(512), 0, stream,
                       sorted, binstart, minarr);
    hipLaunchKernelGGL(reduce_out_kernel, dim3(B_), dim3(1024), 0, stream,
                       segcounts, minarr, out);
}